// Round 16
// baseline (32.701 us; speedup 1.0000x reference)
//
#include <hip/hip_runtime.h>

typedef unsigned long long u64;
typedef unsigned int u32;

#define NB 64      // graphs
#define NN 128     // nodes per graph
#define NITER 5
#define NGEN 6     // initial labels + 5 WL iterations
#define SALT 0xD1B54A32D192ED03ULL
#define TSLOTS 256

__device__ __forceinline__ u64 mix64(u64 x) {
    u64 z = x + 0x9E3779B97F4A7C15ULL;
    z = (z ^ (z >> 30)) * 0xBF58476D1CE4E5B9ULL;
    z = (z ^ (z >> 27)) * 0x94D049BB133111EBULL;
    return z ^ (z >> 31);
}

// D1: 384 blocks x 512 threads, one per (graph b, generation gen).
// Each block independently recomputes the WL chain up to its generation
// (coalesced ballot pack + R7's proven ctz quarter-walk), then builds a
// compact 256-slot hash table {key32, cnt32}, exports it + u32 labels +
// Kpart[b][gen] = sum cnt^2. No inter-block deps; idempotent in effect.
__global__ __launch_bounds__(512) void wl_gen(const float* __restrict__ adj,
                                              const int* __restrict__ labels,
                                              uint2* __restrict__ tabg,
                                              u32* __restrict__ labels32,
                                              float* __restrict__ Kpart,
                                              float* __restrict__ out) {
    const int blk = blockIdx.x;       // b*NGEN + gen
    const int b   = blk / NGEN;
    const int gen = blk % NGEN;       // iterations to run
    const int t = threadIdx.x;
    const int wave = t >> 6;          // 0..7
    const int lane = t & 63;
    const int u = t & 127;            // node
    const int q = t >> 7;             // quarter 0..3

    __shared__ u64 bits_sh[NN][2];    // 2 KiB row masks
    __shared__ u64 gsh[NN];           // 1 KiB neighbor feed
    __shared__ u64 psum[3][NN];       // 3 KiB quarter partials
    __shared__ u32 keys[TSLOTS];      // 1 KiB
    __shared__ u32 cnts[TSLOTS];      // 1 KiB
    __shared__ u32 part[8];

    // ---- coalesced ballot pack (only if we run iterations) ----
    if (gen > 0) {
        const float* abase = adj + (size_t)b * NN * NN;
        #pragma unroll
        for (int k = 0; k < 16; ++k) {
            const int row = wave * 16 + k;
            const float* arow = abase + (size_t)row * NN;
            u64 m0 = __ballot(arow[lane] > 0.5f);
            u64 m1 = __ballot(arow[64 + lane] > 0.5f);
            if (lane == 0) { bits_sh[row][0] = m0; bits_sh[row][1] = m1; }
        }
    }
    if (t < TSLOTS) { keys[t] = 0u; cnts[t] = 0u; }

    u64 h = mix64((u64)(u32)labels[b * NN + u]);   // same value across quarters
    __syncthreads();

    u32 qm = 0;
    if (gen > 0) qm = (u32)(bits_sh[u][q >> 1] >> ((q & 1) * 32));

    for (int it = 0; it < gen; ++it) {
        if (q == 0) gsh[u] = mix64(h ^ SALT);
        __syncthreads();
        u64 s = 0;
        {
            u32 mm = qm;
            const u64* gp = gsh + q * 32;
            while (mm) { int j = __builtin_ctz(mm); mm &= mm - 1; s += gp[j]; }
        }
        if (q) psum[q - 1][u] = s;
        __syncthreads();
        if (q == 0) h = mix64(mix64(h) + s + psum[0][u] + psum[1][u] + psum[2][u]);
        // q>0 copies of h go stale; only q==0 uses h below.
    }

    // ---- build compact table: q==0 threads hold the 128 labels ----
    if (q == 0) {
        const u32 key = (u32)h;       // 32-bit key; low 8 bits = slot hash
        u32 s = key & (TSLOTS - 1);
        for (;;) {
            u32 old = atomicCAS(&keys[s], 0u, key);
            if (old == 0u || old == key) { atomicAdd(&cnts[s], 1u); break; }
            s = (s + 1) & (TSLOTS - 1);
        }
    }
    __syncthreads();

    // ---- export table + labels32 + Kpart ----
    if (t < TSLOTS) {
        const u32 kk = keys[t];
        const u32 cc = cnts[t];
        tabg[(size_t)blk * TSLOTS + t] = make_uint2(kk, cc);
        u32 acc = cc * cc;
        #pragma unroll
        for (int off = 32; off > 0; off >>= 1) acc += __shfl_down(acc, off);
        if ((t & 63) == 0) part[t >> 6] = acc;
    }
    if (t < NN) labels32[(size_t)blk * NN + t] = (u32)h;
    __syncthreads();
    if (t == 0) {
        Kpart[blk] = (float)(part[0] + part[1] + part[2] + part[3]);
        if (gen == 0) out[b * NB + b] = 1.0f;
    }
}

// D2: 2048 blocks x 256 threads; block p = (b2 = p>>5, i = p&31) handles
// pairs (b1a, b2) and (b1b, b2) with b1a = b2+1+2i, b1b = b1a+1 (skip > 63).
// Stages b2's 6 compact tables ONCE (12 KiB), probes with up to two b1
// label sets (u32, 3 KiB each), normalizes via Kpart, writes both triangles.
__global__ __launch_bounds__(256) void wl_pairs(const uint2* __restrict__ tabg,
                                                const u32* __restrict__ labels32,
                                                const float* __restrict__ Kpart,
                                                float* __restrict__ out) {
    const int p = blockIdx.x;
    const int b2 = p >> 5;
    const int i  = p & 31;
    const int b1a = b2 + 1 + 2 * i;
    if (b1a > 63) return;             // block-uniform early exit
    const int b1b = b1a + 1;          // valid iff <= 63
    const bool hasB = (b1b <= 63);

    const int t = threadIdx.x;
    __shared__ uint2 tab[NGEN * TSLOTS];  // 12 KiB
    __shared__ u32 red[8];
    __shared__ float dsh[3 * NGEN];

    if (t < 3 * NGEN) {               // Kdiag partials: b2 / b1a / b1b
        const int which = t / NGEN;
        const int g = t % NGEN;
        const int bb = (which == 0) ? b2 : (which == 1) ? b1a : (hasB ? b1b : b1a);
        dsh[t] = Kpart[bb * NGEN + g];
    }
    {   // stage b2's tables: 1536 uint2 = 768 uint4 over 256 threads
        const uint4* src = (const uint4*)(tabg + (size_t)b2 * NGEN * TSLOTS);
        uint4* dst = (uint4*)tab;
        #pragma unroll
        for (int k = 0; k < 3; ++k) dst[t + 256 * k] = src[t + 256 * k];
    }
    __syncthreads();

    u32 ca = 0, cb = 0;
    const u32* la = labels32 + (size_t)b1a * (NGEN * NN);
    #pragma unroll
    for (int k = 0; k < 3; ++k) {
        const int idx = t + 256 * k;          // 0..767, gen = idx>>7
        const int base = (idx >> 7) * TSLOTS;
        const u32 a = la[idx];
        u32 s = a & (TSLOTS - 1);
        for (;;) {
            const uint2 kv = tab[base + s];
            if (kv.x == a) { ca += kv.y; break; }
            if (kv.x == 0u) break;
            s = (s + 1) & (TSLOTS - 1);
        }
    }
    if (hasB) {
        const u32* lb = labels32 + (size_t)b1b * (NGEN * NN);
        #pragma unroll
        for (int k = 0; k < 3; ++k) {
            const int idx = t + 256 * k;
            const int base = (idx >> 7) * TSLOTS;
            const u32 a = lb[idx];
            u32 s = a & (TSLOTS - 1);
            for (;;) {
                const uint2 kv = tab[base + s];
                if (kv.x == a) { cb += kv.y; break; }
                if (kv.x == 0u) break;
                s = (s + 1) & (TSLOTS - 1);
            }
        }
    }

    #pragma unroll
    for (int off = 32; off > 0; off >>= 1) {
        ca += __shfl_down(ca, off);
        cb += __shfl_down(cb, off);
    }
    if ((t & 63) == 0) { red[t >> 6] = ca; red[4 + (t >> 6)] = cb; }
    __syncthreads();
    if (t == 0) {
        float d2s = 0.f, d1a = 0.f, d1b = 0.f;
        #pragma unroll
        for (int g = 0; g < NGEN; ++g) {
            d2s += dsh[g]; d1a += dsh[NGEN + g]; d1b += dsh[2 * NGEN + g];
        }
        const float va = (float)(red[0] + red[1] + red[2] + red[3])
                       / (sqrtf(d1a) * sqrtf(d2s));
        out[b1a * NB + b2] = va;
        out[b2 * NB + b1a] = va;
        if (hasB) {
            const float vb = (float)(red[4] + red[5] + red[6] + red[7])
                           / (sqrtf(d1b) * sqrtf(d2s));
            out[b1b * NB + b2] = vb;
            out[b2 * NB + b1b] = vb;
        }
    }
}

extern "C" void kernel_launch(void* const* d_in, const int* in_sizes, int n_in,
                              void* d_out, int out_size, void* d_ws, size_t ws_size,
                              hipStream_t stream) {
    const float* adj   = (const float*)d_in[0];   // [64,128,128] fp32 (0/1)
    const int*  labels = (const int*)d_in[1];     // [64,128] int32
    float* out = (float*)d_out;                   // [64,64] fp32

    char* ws = (char*)d_ws;
    uint2* tabg     = (uint2*)ws;                    // 384*256*8 = 768 KiB
    u32*   labels32 = (u32*)(ws + 1024 * 1024);      // 384*128*4 = 192 KiB
    float* Kpart    = (float*)(ws + 1536 * 1024);    // 1.5 KiB

    wl_gen  <<<NB * NGEN, 512, 0, stream>>>(adj, labels, tabg, labels32, Kpart, out);
    wl_pairs<<<NB * 32,   256, 0, stream>>>(tabg, labels32, Kpart, out);
}

// Round 17
// 31.739 us; speedup vs baseline: 1.0303x; 1.0303x over previous
//
#include <hip/hip_runtime.h>

typedef unsigned long long u64;
typedef unsigned int u32;

#define NB 64      // graphs
#define NN 128     // nodes per graph
#define NITER 5
#define NGEN 6     // initial labels + 5 WL iterations
#define SALT 0xD1B54A32D192ED03ULL
#define TSLOTS 256

__device__ __forceinline__ u64 mix64(u64 x) {
    u64 z = x + 0x9E3779B97F4A7C15ULL;
    z = (z ^ (z >> 30)) * 0xBF58476D1CE4E5B9ULL;
    z = (z ^ (z >> 27)) * 0x94D049BB133111EBULL;
    return z ^ (z >> 31);
}

// D1: 384 blocks x 512 threads, one per (graph b, generation gen).
// Each block independently recomputes the WL chain up to its generation using
// the PROVEN float4 quarter-mask pack (independent pipelined loads — ballot
// pack regresses: R12/R16) + ctz quarter-walk, then builds a compact 256-slot
// {key32,cnt32} table, exports it + u32 labels + Kpart = sum cnt^2.
__global__ __launch_bounds__(512) void wl_gen(const float* __restrict__ adj,
                                              const int* __restrict__ labels,
                                              uint2* __restrict__ tabg,
                                              u32* __restrict__ labels32,
                                              float* __restrict__ Kpart,
                                              float* __restrict__ out) {
    const int blk = blockIdx.x;       // b*NGEN + gen
    const int b   = blk / NGEN;
    const int gen = blk % NGEN;       // iterations to run
    const int t = threadIdx.x;
    const int u = t & 127;            // node
    const int q = t >> 7;             // quarter 0..3

    __shared__ u64 gsh[NN];           // 1 KiB neighbor feed
    __shared__ u64 psum[3][NN];       // 3 KiB quarter partials
    __shared__ u32 keys[TSLOTS];      // 1 KiB
    __shared__ u32 cnts[TSLOTS];      // 1 KiB
    __shared__ u32 part[4];

    // ---- register adjacency quarter-mask via pipelined float4 loads ----
    u32 qm = 0;
    if (gen > 0) {
        const float* rowp = adj + ((size_t)b * NN + u) * NN + q * 32;
        #pragma unroll
        for (int k = 0; k < 8; ++k) {
            const float4 v = *(const float4*)(rowp + 4 * k);
            qm |= (v.x > 0.5f ? 1u : 0u) << (4 * k);
            qm |= (v.y > 0.5f ? 1u : 0u) << (4 * k + 1);
            qm |= (v.z > 0.5f ? 1u : 0u) << (4 * k + 2);
            qm |= (v.w > 0.5f ? 1u : 0u) << (4 * k + 3);
        }
    }
    if (t < TSLOTS) { keys[t] = 0u; cnts[t] = 0u; }

    u64 h = mix64((u64)(u32)labels[b * NN + u]);   // same across quarters
    __syncthreads();

    for (int it = 0; it < gen; ++it) {
        if (q == 0) gsh[u] = mix64(h ^ SALT);
        __syncthreads();
        u64 s = 0;
        {
            u32 mm = qm;
            const u64* gp = gsh + q * 32;
            while (mm) { int j = __builtin_ctz(mm); mm &= mm - 1; s += gp[j]; }
        }
        if (q) psum[q - 1][u] = s;
        __syncthreads();
        if (q == 0) h = mix64(mix64(h) + s + psum[0][u] + psum[1][u] + psum[2][u]);
        // q>0 copies of h go stale; only q==0 uses h below.
    }

    // ---- build compact table: q==0 threads hold the 128 labels ----
    if (q == 0) {
        const u32 key = (u32)h;       // 32-bit key; low 8 bits = slot hash
        u32 s = key & (TSLOTS - 1);
        for (;;) {
            u32 old = atomicCAS(&keys[s], 0u, key);
            if (old == 0u || old == key) { atomicAdd(&cnts[s], 1u); break; }
            s = (s + 1) & (TSLOTS - 1);
        }
    }
    __syncthreads();

    // ---- export table + labels32 + Kpart ----
    if (t < TSLOTS) {
        const u32 kk = keys[t];
        const u32 cc = cnts[t];
        tabg[(size_t)blk * TSLOTS + t] = make_uint2(kk, cc);
        u32 acc = cc * cc;
        #pragma unroll
        for (int off = 32; off > 0; off >>= 1) acc += __shfl_down(acc, off);
        if ((t & 63) == 0) part[t >> 6] = acc;
    }
    if (t < NN && q == 0) labels32[(size_t)blk * NN + t] = (u32)h;
    __syncthreads();
    if (t == 0) {
        Kpart[blk] = (float)(part[0] + part[1] + part[2] + part[3]);
        if (gen == 0) out[b * NB + b] = 1.0f;
    }
}

// D2 (R16 verbatim): 2048 blocks x 256 threads; block p = (b2 = p>>5, i = p&31)
// handles pairs (b1a,b2),(b1b,b2), b1a = b2+1+2i, b1b = b1a+1 (skip > 63).
// Stage b2's 6 compact tables once (12 KiB), probe with b1 labels (u32).
__global__ __launch_bounds__(256) void wl_pairs(const uint2* __restrict__ tabg,
                                                const u32* __restrict__ labels32,
                                                const float* __restrict__ Kpart,
                                                float* __restrict__ out) {
    const int p = blockIdx.x;
    const int b2 = p >> 5;
    const int i  = p & 31;
    const int b1a = b2 + 1 + 2 * i;
    if (b1a > 63) return;             // block-uniform early exit
    const int b1b = b1a + 1;
    const bool hasB = (b1b <= 63);

    const int t = threadIdx.x;
    __shared__ uint2 tab[NGEN * TSLOTS];  // 12 KiB
    __shared__ u32 red[8];
    __shared__ float dsh[3 * NGEN];

    if (t < 3 * NGEN) {               // Kdiag partials: b2 / b1a / b1b
        const int which = t / NGEN;
        const int g = t % NGEN;
        const int bb = (which == 0) ? b2 : (which == 1) ? b1a : (hasB ? b1b : b1a);
        dsh[t] = Kpart[bb * NGEN + g];
    }
    {   // stage b2's tables: 1536 uint2 = 768 uint4 over 256 threads
        const uint4* src = (const uint4*)(tabg + (size_t)b2 * NGEN * TSLOTS);
        uint4* dst = (uint4*)tab;
        #pragma unroll
        for (int k = 0; k < 3; ++k) dst[t + 256 * k] = src[t + 256 * k];
    }
    __syncthreads();

    u32 ca = 0, cb = 0;
    const u32* la = labels32 + (size_t)b1a * (NGEN * NN);
    #pragma unroll
    for (int k = 0; k < 3; ++k) {
        const int idx = t + 256 * k;          // 0..767, gen = idx>>7
        const int base = (idx >> 7) * TSLOTS;
        const u32 a = la[idx];
        u32 s = a & (TSLOTS - 1);
        for (;;) {
            const uint2 kv = tab[base + s];
            if (kv.x == a) { ca += kv.y; break; }
            if (kv.x == 0u) break;
            s = (s + 1) & (TSLOTS - 1);
        }
    }
    if (hasB) {
        const u32* lb = labels32 + (size_t)b1b * (NGEN * NN);
        #pragma unroll
        for (int k = 0; k < 3; ++k) {
            const int idx = t + 256 * k;
            const int base = (idx >> 7) * TSLOTS;
            const u32 a = lb[idx];
            u32 s = a & (TSLOTS - 1);
            for (;;) {
                const uint2 kv = tab[base + s];
                if (kv.x == a) { cb += kv.y; break; }
                if (kv.x == 0u) break;
                s = (s + 1) & (TSLOTS - 1);
            }
        }
    }

    #pragma unroll
    for (int off = 32; off > 0; off >>= 1) {
        ca += __shfl_down(ca, off);
        cb += __shfl_down(cb, off);
    }
    if ((t & 63) == 0) { red[t >> 6] = ca; red[4 + (t >> 6)] = cb; }
    __syncthreads();
    if (t == 0) {
        float d2s = 0.f, d1a = 0.f, d1b = 0.f;
        #pragma unroll
        for (int g = 0; g < NGEN; ++g) {
            d2s += dsh[g]; d1a += dsh[NGEN + g]; d1b += dsh[2 * NGEN + g];
        }
        const float va = (float)(red[0] + red[1] + red[2] + red[3])
                       / (sqrtf(d1a) * sqrtf(d2s));
        out[b1a * NB + b2] = va;
        out[b2 * NB + b1a] = va;
        if (hasB) {
            const float vb = (float)(red[4] + red[5] + red[6] + red[7])
                           / (sqrtf(d1b) * sqrtf(d2s));
            out[b1b * NB + b2] = vb;
            out[b2 * NB + b1b] = vb;
        }
    }
}

extern "C" void kernel_launch(void* const* d_in, const int* in_sizes, int n_in,
                              void* d_out, int out_size, void* d_ws, size_t ws_size,
                              hipStream_t stream) {
    const float* adj   = (const float*)d_in[0];   // [64,128,128] fp32 (0/1)
    const int*  labels = (const int*)d_in[1];     // [64,128] int32
    float* out = (float*)d_out;                   // [64,64] fp32

    char* ws = (char*)d_ws;
    uint2* tabg     = (uint2*)ws;                    // 384*256*8 = 768 KiB
    u32*   labels32 = (u32*)(ws + 1024 * 1024);      // 384*128*4 = 192 KiB
    float* Kpart    = (float*)(ws + 1536 * 1024);    // 1.5 KiB

    wl_gen  <<<NB * NGEN, 512, 0, stream>>>(adj, labels, tabg, labels32, Kpart, out);
    wl_pairs<<<NB * 32,   256, 0, stream>>>(tabg, labels32, Kpart, out);
}